// Round 4
// baseline (393.619 us; speedup 1.0000x reference)
//
#include <hip/hip_runtime.h>

// metaCLF: per-voxel MLP filter gen + filtering. MFMA, barrier-free.
// x: [2,32,96^3] f32, d_all: [2,6,96^3] f32
// W1:[16,2] W2:[3,16] G1:[32,27] G2:[64,32] G3:[32,64] -> out: [2,1,96^3] f32
//
// Round 10 — RETRY of the R9 CALIBRATION ROUND (R9 hit an MI355X container
// infra failure before producing any timing; source below is bit-identical).
// Context: R6 (LDS-heavy), R7 (x-prefetch), R8 (all-register MFMA chain) all
// landed at 347.7-349.4 us headline despite removing 44/60 DS ops and ~120
// VALU insts. Two surviving theories:
//   (a) kernel ~80us, DRAM-row-thrash bound on the 32-plane strided x read
//       (unchanged in all rounds) at ~3.3 TB/s effective;
//   (b) kernel ~45-50us (HBM floor), headline dominated by harness fills
//       (2 x 133us) + small-dispatch overhead.
// These demand opposite next actions. This round launches the BIT-IDENTICAL
// R8 kernel TWICE (deterministic, writes only `out` -> idempotent, stream-
// serialized, graph-capture safe). headline - 349 = T_metaclf, measured
// directly. (a) -> ~430us; (b) -> ~395-400us; unchanged -> harness model
// wrong. Kernel body is unchanged from R8 (channel-permuted weight tiles,
// register-resident G1->G2->G3 chain, quad-shuffle final dot).

typedef _Float16 f16x8 __attribute__((ext_vector_type(8)));
typedef _Float16 f16x4 __attribute__((ext_vector_type(4)));
typedef float    f32x4 __attribute__((ext_vector_type(4)));

constexpr int V3   = 96 * 96 * 96;   // 884736
constexpr int NVOX = 2 * V3;         // 1769472
constexpr int TV   = 256;            // voxels per block
constexpr int NBLK = NVOX / TV;      // 6912
constexpr int S    = 72;             // LDS row stride, f16 units (144 B)

constexpr float SCALE     = 16384.f;
constexpr float INV_SCALE = 1.f / 16384.f;

// ws fragment table: 10 tiles x 64 lanes x 8 f16 = 10240 B
// tiles: 0,1 = G1 ; 2..5 = G2 ; 6..9 = G3 (kh*2+half) -- all row-PERMUTED:
// tile row m corresponds to output channel 8*(m>>2) + (m&3) + 4*odd (+32 hi).
constexpr int N_TILES  = 10;
constexpr int WS_BYTES = N_TILES * 64 * 8 * 2;

#define LDS_FENCE()  asm volatile("s_waitcnt lgkmcnt(0)" ::: "memory")
#define ISSUE_FENCE() asm volatile("" ::: "memory")

__device__ __forceinline__ f16x8 build_frag(int tile, int m_, int quad,
                                            const float* __restrict__ G1,
                                            const float* __restrict__ G2,
                                            const float* __restrict__ G3) {
    f16x8 v;
    const int k0 = quad * 8;
    const int g8 = (m_ >> 2) * 8 + (m_ & 3);   // permuted channel base
#pragma unroll
    for (int j = 0; j < 8; ++j) {
        float f = 0.f;
        const int k = k0 + j;
        if (tile < 2) {                         // G1: ch = g8 + 4*tile, k over 27
            const int ch = g8 + tile * 4;
            if (k < 27) f = G1[ch * 27 + k];
        } else if (tile < 6) {                  // G2: T=tile-2
            const int T  = tile - 2;
            const int ch = (T >> 1) * 32 + (T & 1) * 4 + g8;
            f = G2[ch * 32 + k];
        } else {                                // G3: U=tile-6, kh=U>>1, half=U&1
            const int U  = tile - 6;
            const int ch = g8 + (U & 1) * 4;
            f = G3[ch * 64 + (U >> 1) * 32 + k];
        }
        v[j] = (_Float16)f;
    }
    return v;
}

__global__ __launch_bounds__(256) void pack_weights(
    const float* __restrict__ G1, const float* __restrict__ G2,
    const float* __restrict__ G3, _Float16* __restrict__ wf)
{
    for (int slot = threadIdx.x; slot < N_TILES * 64; slot += 256) {
        const int tile = slot >> 6;
        const int lane = slot & 63;
        const f16x8 v = build_frag(tile, lane & 15, lane >> 4, G1, G2, G3);
        *(f16x8*)&wf[slot * 8] = v;
    }
}

template <bool USE_WS>
__global__ __launch_bounds__(256, 4) void metaclf_mfma4(
    const float* __restrict__ x,
    const float* __restrict__ d_all,
    const float* __restrict__ W1,
    const float* __restrict__ W2,
    const float* __restrict__ G1,
    const float* __restrict__ G2,
    const float* __restrict__ G3,
    const _Float16* __restrict__ wf,
    float* __restrict__ out)
{
    __shared__ _Float16 lds[TV * S];           // 36,864 B (kron transpose only)

    const int t    = threadIdx.x;
    const int lane = t & 63;
    const int wave = t >> 6;
    const int n16  = lane & 15;
    const int quad = lane >> 4;
    const int g0   = wave * 4;                 // first 16-voxel group of this wave

    const int gidx = blockIdx.x * TV + t;
    const int b = (gidx >= V3) ? 1 : 0;        // uniform per block
    const int v = gidx - b * V3;               // voxel within batch
    const int vw = v - lane;                   // wave's voxel base

    // ---- load order: d_all (needed first) -> frags -> x (needed last).
    // vmcnt retires in issue order, so this keeps x in flight while frags
    // are consumed (vmcnt(32)), and frags in flight during encode. ----
    float dv[6];
#pragma unroll
    for (int i = 0; i < 6; ++i) dv[i] = d_all[(size_t)(b * 6 + i) * V3 + v];
    ISSUE_FENCE();

    f16x8 wfr[10];                             // all weight frags, loaded ONCE
    if constexpr (USE_WS) {
#pragma unroll
        for (int i = 0; i < N_TILES; ++i)
            wfr[i] = *(const f16x8*)&wf[(i * 64 + lane) * 8];
    } else {
#pragma unroll
        for (int i = 0; i < N_TILES; ++i)
            wfr[i] = build_frag(i, n16, quad, G1, G2, G3);
    }
    ISSUE_FENCE();

    // x prefetch: thread (n16,quad) needs channels 8q..8q+7 of the 4 voxels
    // vw + g*16 + n16 (matches the permuted G3 output it will hold).
    float xv[32];
    {
        const float* xb = x + ((size_t)(b * 32 + 8 * quad)) * V3 + (vw + n16);
#pragma unroll
        for (int g = 0; g < 4; ++g)
#pragma unroll
            for (int j = 0; j < 8; ++j)
                xv[g * 8 + j] = xb[(size_t)j * V3 + g * 16];
    }

    // ========== Phase 1: encode + kron (fp32, exact), scaled -> E (f16) ==========
    {
        float e[3][3];
#pragma unroll
        for (int a = 0; a < 3; ++a) {
            const float d0 = dv[2 * a], d1 = dv[2 * a + 1];
            float a0 = 0.f, a1 = 0.f, a2 = 0.f;
#pragma unroll
            for (int k = 0; k < 16; ++k) {
                const float tt = fmaxf(fmaf(W1[k * 2], d0, W1[k * 2 + 1] * d1), 0.f);
                a0 = fmaf(W2[0 * 16 + k], tt, a0);
                a1 = fmaf(W2[1 * 16 + k], tt, a1);
                a2 = fmaf(W2[2 * 16 + k], tt, a2);
            }
            e[a][0] = a0; e[a][1] = a1; e[a][2] = a2;
        }
        _Float16 row[32];
#pragma unroll
        for (int i = 0; i < 3; ++i)
#pragma unroll
            for (int j = 0; j < 3; ++j) {
                const float p = e[0][i] * e[1][j] * SCALE;
#pragma unroll
                for (int k = 0; k < 3; ++k)
                    row[i * 9 + j * 3 + k] = (_Float16)(p * e[2][k]);
            }
#pragma unroll
        for (int m = 27; m < 32; ++m) row[m] = (_Float16)0.f;

        f16x8* dst = (f16x8*)&lds[t * S];
#pragma unroll
        for (int i = 0; i < 4; ++i) dst[i] = ((const f16x8*)row)[i];
    }
    LDS_FENCE();   // wave-local: own 64 rows fully written

    // ========== Phases 2-5 fused: all-register MFMA chain per group ==========
    float res = 0.f;
#pragma unroll
    for (int g = 0; g < 4; ++g) {
        const int rowv = (g0 + g) * 16;
        // B-frag of E for this group (k = quad*8+j over kron dims)
        const f16x8 ef = *(const f16x8*)&lds[(rowv + n16) * S + quad * 8];

        // G1 (27->32): c0 -> ch 8q+r, c1 -> ch 8q+4+r of voxel rowv+n16
        f32x4 c0 = {0.f, 0.f, 0.f, 0.f}, c1 = {0.f, 0.f, 0.f, 0.f};
        c0 = __builtin_amdgcn_mfma_f32_16x16x32_f16(wfr[0], ef, c0, 0, 0, 0);
        c1 = __builtin_amdgcn_mfma_f32_16x16x32_f16(wfr[1], ef, c1, 0, 0, 0);
        f16x8 b2;
#pragma unroll
        for (int r = 0; r < 4; ++r) {
            b2[r]     = (_Float16)fmaxf(c0[r], 0.f);
            b2[4 + r] = (_Float16)fmaxf(c1[r], 0.f);
        }
        // b2 = channels 8q..8q+7 == B-frag (k=8q+j) for G2. No LDS.

        // G2 (32->64): h[0]->8q+r h[1]->8q+4+r h[2]->32+8q+r h[3]->32+8q+4+r
        f32x4 h[4];
#pragma unroll
        for (int q4 = 0; q4 < 4; ++q4) {
            h[q4] = (f32x4){0.f, 0.f, 0.f, 0.f};
            h[q4] = __builtin_amdgcn_mfma_f32_16x16x32_f16(wfr[2 + q4], b2, h[q4], 0, 0, 0);
        }
        f16x8 a0, a1;
#pragma unroll
        for (int r = 0; r < 4; ++r) {
            a0[r]     = (_Float16)fmaxf(h[0][r], 0.f);
            a0[4 + r] = (_Float16)fmaxf(h[1][r], 0.f);
            a1[r]     = (_Float16)fmaxf(h[2][r], 0.f);
            a1[4 + r] = (_Float16)fmaxf(h[3][r], 0.f);
        }
        // a0 = ch 8q..8q+7 (k-half 0), a1 = ch 32+8q..+7 (k-half 1). No LDS.

        // G3 (64->32): d0 -> F[8q+r], d1 -> F[8q+4+r] of voxel rowv+n16
        f32x4 d0 = {0.f, 0.f, 0.f, 0.f}, d1 = {0.f, 0.f, 0.f, 0.f};
        d0 = __builtin_amdgcn_mfma_f32_16x16x32_f16(wfr[6], a0, d0, 0, 0, 0);
        d0 = __builtin_amdgcn_mfma_f32_16x16x32_f16(wfr[8], a1, d0, 0, 0, 0);
        d1 = __builtin_amdgcn_mfma_f32_16x16x32_f16(wfr[7], a0, d1, 0, 0, 0);
        d1 = __builtin_amdgcn_mfma_f32_16x16x32_f16(wfr[9], a1, d1, 0, 0, 0);

        // partial dot: this thread's 8 channels of voxel rowv+n16
        float p = 0.f;
#pragma unroll
        for (int r = 0; r < 4; ++r) {
            p = fmaf(d0[r], xv[g * 8 + r],     p);
            p = fmaf(d1[r], xv[g * 8 + 4 + r], p);
        }
        // reduce across the 4 quads holding this voxel's other channels
        p += __shfl_xor(p, 16);
        p += __shfl_xor(p, 32);
        if (g == quad) res = p;   // thread's own voxel is in group g==quad
    }

    out[(size_t)b * V3 + v] = res * INV_SCALE;
}

extern "C" void kernel_launch(void* const* d_in, const int* in_sizes, int n_in,
                              void* d_out, int out_size, void* d_ws, size_t ws_size,
                              hipStream_t stream) {
    const float* x     = (const float*)d_in[0];
    const float* d_all = (const float*)d_in[1];
    const float* W1    = (const float*)d_in[2];
    const float* W2    = (const float*)d_in[3];
    const float* G1    = (const float*)d_in[4];
    const float* G2    = (const float*)d_in[5];
    const float* G3    = (const float*)d_in[6];
    float* out = (float*)d_out;

    // CALIBRATION: metaclf launched TWICE (deterministic + idempotent).
    // headline - 349us = T_metaclf, measured through the harness itself.
    if (ws_size >= (size_t)WS_BYTES) {
        _Float16* wf = (_Float16*)d_ws;
        pack_weights<<<1, 256, 0, stream>>>(G1, G2, G3, wf);
        metaclf_mfma4<true><<<NBLK, 256, 0, stream>>>(
            x, d_all, W1, W2, G1, G2, G3, wf, out);
        metaclf_mfma4<true><<<NBLK, 256, 0, stream>>>(
            x, d_all, W1, W2, G1, G2, G3, wf, out);
    } else {
        metaclf_mfma4<false><<<NBLK, 256, 0, stream>>>(
            x, d_all, W1, W2, G1, G2, G3, nullptr, out);
        metaclf_mfma4<false><<<NBLK, 256, 0, stream>>>(
            x, d_all, W1, W2, G1, G2, G3, nullptr, out);
    }
}

// Round 5
// 347.829 us; speedup vs baseline: 1.1316x; 1.1316x over previous
//
#include <hip/hip_runtime.h>

// metaCLF: per-voxel MLP filter gen + filtering. MFMA, barrier-free.
// x: [2,32,96^3] f32, d_all: [2,6,96^3] f32
// W1:[16,2] W2:[3,16] G1:[32,27] G2:[64,32] G3:[32,64] -> out: [2,1,96^3] f32
//
// Round 11 — FINAL (revert of the R10 calibration double-launch).
// R10 measured T_metaclf = 393.6 - 349.1 = 44.5 us via the double-launch
// delta. Irreducible traffic = x 226.5 MB + d_all 42.5 MB + out 7.1 MB =
// 276 MB -> 43.8 us floor at the 6.3 TB/s achievable HBM ceiling. The kernel
// is at >=98% of the memory roofline; the remaining ~305 us of the headline
// is harness fixed cost (2x 133us re-poison fills + ~47 small dispatches),
// invisible to kernel changes. This explains R7/R8 neutrality: the kernel
// was already roofline-bound when this session started.
//
// Kernel structure (R8): channel-permuted weight tiles so each MFMA's C/D
// layout IS the next MFMA's B-frag layout -- tile row m -> channel
// 8*(m>>2)+(m&3) (+4 odd tiles, +32 hi) -- letting G1->G2->G3 chain entirely
// in registers (relu+cvt accumulators feed straight back as B operands).
// LDS used only for the kron transpose (16 DS ops/wave, stride-72 f16 rows,
// wave-private 64 voxels, no barriers). Final dot stays in C-layout: thread
// dots its 8 channels, __shfl_xor(16/32) quad-reduce, one coalesced store.
// Loads pinned d_all -> weight frags (once) -> x so vmcnt in-order retire
// keeps x in flight under phase-1 encode. Activations scaled 2^14 (relu
// pos-homogeneous); weights prepacked to d_ws by pack_weights.

typedef _Float16 f16x8 __attribute__((ext_vector_type(8)));
typedef _Float16 f16x4 __attribute__((ext_vector_type(4)));
typedef float    f32x4 __attribute__((ext_vector_type(4)));

constexpr int V3   = 96 * 96 * 96;   // 884736
constexpr int NVOX = 2 * V3;         // 1769472
constexpr int TV   = 256;            // voxels per block
constexpr int NBLK = NVOX / TV;      // 6912
constexpr int S    = 72;             // LDS row stride, f16 units (144 B)

constexpr float SCALE     = 16384.f;
constexpr float INV_SCALE = 1.f / 16384.f;

// ws fragment table: 10 tiles x 64 lanes x 8 f16 = 10240 B
// tiles: 0,1 = G1 ; 2..5 = G2 ; 6..9 = G3 (kh*2+half) -- all row-PERMUTED:
// tile row m corresponds to output channel 8*(m>>2) + (m&3) + 4*odd (+32 hi).
constexpr int N_TILES  = 10;
constexpr int WS_BYTES = N_TILES * 64 * 8 * 2;

#define LDS_FENCE()  asm volatile("s_waitcnt lgkmcnt(0)" ::: "memory")
#define ISSUE_FENCE() asm volatile("" ::: "memory")

__device__ __forceinline__ f16x8 build_frag(int tile, int m_, int quad,
                                            const float* __restrict__ G1,
                                            const float* __restrict__ G2,
                                            const float* __restrict__ G3) {
    f16x8 v;
    const int k0 = quad * 8;
    const int g8 = (m_ >> 2) * 8 + (m_ & 3);   // permuted channel base
#pragma unroll
    for (int j = 0; j < 8; ++j) {
        float f = 0.f;
        const int k = k0 + j;
        if (tile < 2) {                         // G1: ch = g8 + 4*tile, k over 27
            const int ch = g8 + tile * 4;
            if (k < 27) f = G1[ch * 27 + k];
        } else if (tile < 6) {                  // G2: T=tile-2
            const int T  = tile - 2;
            const int ch = (T >> 1) * 32 + (T & 1) * 4 + g8;
            f = G2[ch * 32 + k];
        } else {                                // G3: U=tile-6, kh=U>>1, half=U&1
            const int U  = tile - 6;
            const int ch = g8 + (U & 1) * 4;
            f = G3[ch * 64 + (U >> 1) * 32 + k];
        }
        v[j] = (_Float16)f;
    }
    return v;
}

__global__ __launch_bounds__(256) void pack_weights(
    const float* __restrict__ G1, const float* __restrict__ G2,
    const float* __restrict__ G3, _Float16* __restrict__ wf)
{
    for (int slot = threadIdx.x; slot < N_TILES * 64; slot += 256) {
        const int tile = slot >> 6;
        const int lane = slot & 63;
        const f16x8 v = build_frag(tile, lane & 15, lane >> 4, G1, G2, G3);
        *(f16x8*)&wf[slot * 8] = v;
    }
}

template <bool USE_WS>
__global__ __launch_bounds__(256, 4) void metaclf_mfma4(
    const float* __restrict__ x,
    const float* __restrict__ d_all,
    const float* __restrict__ W1,
    const float* __restrict__ W2,
    const float* __restrict__ G1,
    const float* __restrict__ G2,
    const float* __restrict__ G3,
    const _Float16* __restrict__ wf,
    float* __restrict__ out)
{
    __shared__ _Float16 lds[TV * S];           // 36,864 B (kron transpose only)

    const int t    = threadIdx.x;
    const int lane = t & 63;
    const int wave = t >> 6;
    const int n16  = lane & 15;
    const int quad = lane >> 4;
    const int g0   = wave * 4;                 // first 16-voxel group of this wave

    const int gidx = blockIdx.x * TV + t;
    const int b = (gidx >= V3) ? 1 : 0;        // uniform per block
    const int v = gidx - b * V3;               // voxel within batch
    const int vw = v - lane;                   // wave's voxel base

    // ---- load order: d_all (needed first) -> frags -> x (needed last).
    // vmcnt retires in issue order, so this keeps x in flight while frags
    // are consumed (vmcnt(32)), and frags in flight during encode. ----
    float dv[6];
#pragma unroll
    for (int i = 0; i < 6; ++i) dv[i] = d_all[(size_t)(b * 6 + i) * V3 + v];
    ISSUE_FENCE();

    f16x8 wfr[10];                             // all weight frags, loaded ONCE
    if constexpr (USE_WS) {
#pragma unroll
        for (int i = 0; i < N_TILES; ++i)
            wfr[i] = *(const f16x8*)&wf[(i * 64 + lane) * 8];
    } else {
#pragma unroll
        for (int i = 0; i < N_TILES; ++i)
            wfr[i] = build_frag(i, n16, quad, G1, G2, G3);
    }
    ISSUE_FENCE();

    // x prefetch: thread (n16,quad) needs channels 8q..8q+7 of the 4 voxels
    // vw + g*16 + n16 (matches the permuted G3 output it will hold).
    float xv[32];
    {
        const float* xb = x + ((size_t)(b * 32 + 8 * quad)) * V3 + (vw + n16);
#pragma unroll
        for (int g = 0; g < 4; ++g)
#pragma unroll
            for (int j = 0; j < 8; ++j)
                xv[g * 8 + j] = xb[(size_t)j * V3 + g * 16];
    }

    // ========== Phase 1: encode + kron (fp32, exact), scaled -> E (f16) ==========
    {
        float e[3][3];
#pragma unroll
        for (int a = 0; a < 3; ++a) {
            const float d0 = dv[2 * a], d1 = dv[2 * a + 1];
            float a0 = 0.f, a1 = 0.f, a2 = 0.f;
#pragma unroll
            for (int k = 0; k < 16; ++k) {
                const float tt = fmaxf(fmaf(W1[k * 2], d0, W1[k * 2 + 1] * d1), 0.f);
                a0 = fmaf(W2[0 * 16 + k], tt, a0);
                a1 = fmaf(W2[1 * 16 + k], tt, a1);
                a2 = fmaf(W2[2 * 16 + k], tt, a2);
            }
            e[a][0] = a0; e[a][1] = a1; e[a][2] = a2;
        }
        _Float16 row[32];
#pragma unroll
        for (int i = 0; i < 3; ++i)
#pragma unroll
            for (int j = 0; j < 3; ++j) {
                const float p = e[0][i] * e[1][j] * SCALE;
#pragma unroll
                for (int k = 0; k < 3; ++k)
                    row[i * 9 + j * 3 + k] = (_Float16)(p * e[2][k]);
            }
#pragma unroll
        for (int m = 27; m < 32; ++m) row[m] = (_Float16)0.f;

        f16x8* dst = (f16x8*)&lds[t * S];
#pragma unroll
        for (int i = 0; i < 4; ++i) dst[i] = ((const f16x8*)row)[i];
    }
    LDS_FENCE();   // wave-local: own 64 rows fully written

    // ========== Phases 2-5 fused: all-register MFMA chain per group ==========
    float res = 0.f;
#pragma unroll
    for (int g = 0; g < 4; ++g) {
        const int rowv = (g0 + g) * 16;
        // B-frag of E for this group (k = quad*8+j over kron dims)
        const f16x8 ef = *(const f16x8*)&lds[(rowv + n16) * S + quad * 8];

        // G1 (27->32): c0 -> ch 8q+r, c1 -> ch 8q+4+r of voxel rowv+n16
        f32x4 c0 = {0.f, 0.f, 0.f, 0.f}, c1 = {0.f, 0.f, 0.f, 0.f};
        c0 = __builtin_amdgcn_mfma_f32_16x16x32_f16(wfr[0], ef, c0, 0, 0, 0);
        c1 = __builtin_amdgcn_mfma_f32_16x16x32_f16(wfr[1], ef, c1, 0, 0, 0);
        f16x8 b2;
#pragma unroll
        for (int r = 0; r < 4; ++r) {
            b2[r]     = (_Float16)fmaxf(c0[r], 0.f);
            b2[4 + r] = (_Float16)fmaxf(c1[r], 0.f);
        }
        // b2 = channels 8q..8q+7 == B-frag (k=8q+j) for G2. No LDS.

        // G2 (32->64): h[0]->8q+r h[1]->8q+4+r h[2]->32+8q+r h[3]->32+8q+4+r
        f32x4 h[4];
#pragma unroll
        for (int q4 = 0; q4 < 4; ++q4) {
            h[q4] = (f32x4){0.f, 0.f, 0.f, 0.f};
            h[q4] = __builtin_amdgcn_mfma_f32_16x16x32_f16(wfr[2 + q4], b2, h[q4], 0, 0, 0);
        }
        f16x8 a0, a1;
#pragma unroll
        for (int r = 0; r < 4; ++r) {
            a0[r]     = (_Float16)fmaxf(h[0][r], 0.f);
            a0[4 + r] = (_Float16)fmaxf(h[1][r], 0.f);
            a1[r]     = (_Float16)fmaxf(h[2][r], 0.f);
            a1[4 + r] = (_Float16)fmaxf(h[3][r], 0.f);
        }
        // a0 = ch 8q..8q+7 (k-half 0), a1 = ch 32+8q..+7 (k-half 1). No LDS.

        // G3 (64->32): d0 -> F[8q+r], d1 -> F[8q+4+r] of voxel rowv+n16
        f32x4 d0 = {0.f, 0.f, 0.f, 0.f}, d1 = {0.f, 0.f, 0.f, 0.f};
        d0 = __builtin_amdgcn_mfma_f32_16x16x32_f16(wfr[6], a0, d0, 0, 0, 0);
        d0 = __builtin_amdgcn_mfma_f32_16x16x32_f16(wfr[8], a1, d0, 0, 0, 0);
        d1 = __builtin_amdgcn_mfma_f32_16x16x32_f16(wfr[7], a0, d1, 0, 0, 0);
        d1 = __builtin_amdgcn_mfma_f32_16x16x32_f16(wfr[9], a1, d1, 0, 0, 0);

        // partial dot: this thread's 8 channels of voxel rowv+n16
        float p = 0.f;
#pragma unroll
        for (int r = 0; r < 4; ++r) {
            p = fmaf(d0[r], xv[g * 8 + r],     p);
            p = fmaf(d1[r], xv[g * 8 + 4 + r], p);
        }
        // reduce across the 4 quads holding this voxel's other channels
        p += __shfl_xor(p, 16);
        p += __shfl_xor(p, 32);
        if (g == quad) res = p;   // thread's own voxel is in group g==quad
    }

    out[(size_t)b * V3 + v] = res * INV_SCALE;
}

extern "C" void kernel_launch(void* const* d_in, const int* in_sizes, int n_in,
                              void* d_out, int out_size, void* d_ws, size_t ws_size,
                              hipStream_t stream) {
    const float* x     = (const float*)d_in[0];
    const float* d_all = (const float*)d_in[1];
    const float* W1    = (const float*)d_in[2];
    const float* W2    = (const float*)d_in[3];
    const float* G1    = (const float*)d_in[4];
    const float* G2    = (const float*)d_in[5];
    const float* G3    = (const float*)d_in[6];
    float* out = (float*)d_out;

    if (ws_size >= (size_t)WS_BYTES) {
        _Float16* wf = (_Float16*)d_ws;
        pack_weights<<<1, 256, 0, stream>>>(G1, G2, G3, wf);
        metaclf_mfma4<true><<<NBLK, 256, 0, stream>>>(
            x, d_all, W1, W2, G1, G2, G3, wf, out);
    } else {
        metaclf_mfma4<false><<<NBLK, 256, 0, stream>>>(
            x, d_all, W1, W2, G1, G2, G3, nullptr, out);
    }
}